// Round 1
// baseline (423.908 us; speedup 1.0000x reference)
//
#include <hip/hip_runtime.h>
#include <hip/hip_bf16.h>

// Fused edge-MLP: out = prelu(prelu([x_i|x_j|ea] @ W1 + b1) @ W2 + b2)
// E=500000, H=1, C=64, CE=16, HID=128, d_in=144. All fp32 in/out; bf16 MFMA inside.

#define E_ROWS 500000
#define TILES  15625          // E_ROWS / 32
#define NBLK   512
#define NWAVES (NBLK * 4)     // 2048 waves, grid-stride over tiles

#define LDW 168               // padded LDS row length (bf16): 84 dwords = 4*odd -> low bank aliasing

typedef short  bf8_t  __attribute__((ext_vector_type(8)));   // 8 x bf16 (bit pattern in i16)
typedef float  f32x16 __attribute__((ext_vector_type(16)));

static __device__ __forceinline__ short f2bf(float v) {
    return (short)__builtin_bit_cast(unsigned short, __float2bfloat16(v));
}

__global__ __launch_bounds__(256, 2)
void message_pass_kernel(const float* __restrict__ x_i,
                         const float* __restrict__ x_j,
                         const float* __restrict__ ea,
                         const float* __restrict__ W1,
                         const float* __restrict__ b1,
                         const float* __restrict__ W2,
                         const float* __restrict__ b2,
                         const float* __restrict__ alpha_p,
                         float* __restrict__ out)
{
    // W1T: rows i=HID idx (128), cols k=0..143 = W1[k][i], col 144 = b1[i], 145..167 = 0
    __shared__ __align__(16) short sW1[128 * LDW];   // 43008 B
    // W2R: rows n=out-col (64), col c stores W2[k][n] with k = c with bits2,3 swapped;
    //      k==128 -> b2[n]; k>128 or c>=144 -> 0
    __shared__ __align__(16) short sW2[64 * LDW];    // 21504 B

    const int tid = threadIdx.x;

    for (int idx = tid; idx < 128 * LDW; idx += 256) {
        int i = idx & 127, c = idx >> 7;             // coalesced global read over i
        float v = 0.f;
        if (c < 144)       v = W1[c * 128 + i];
        else if (c == 144) v = b1[i];
        sW1[i * LDW + c] = f2bf(v);
    }
    for (int idx = tid; idx < 64 * LDW; idx += 256) {
        int i = idx & 63, c = idx >> 6;
        float v = 0.f;
        if (c < 144) {
            int k = (c & ~12) | ((c & 4) << 1) | ((c & 8) >> 1);  // swap bits 2<->3
            if (k < 128)       v = W2[k * 64 + i];
            else if (k == 128) v = b2[i];
        }
        sW2[i * LDW + c] = f2bf(v);
    }
    __syncthreads();

    const float alpha = alpha_p[0];
    const int lane = tid & 63;
    const int l31  = lane & 31;
    const int g2   = lane >> 5;
    const int wv   = blockIdx.x * 4 + (tid >> 6);

    for (int T = wv; T < TILES; T += NWAVES) {
        const size_t row0 = (size_t)T * 32;
        const float* xi  = x_i + (row0 + l31) * 64 + 8 * g2;
        const float* xj  = x_j + (row0 + l31) * 64 + 8 * g2;
        const float* eaR = ea  + (row0 + l31) * 16 + 8 * g2;

        // ---- issue all global loads for this tile (18 x dwordx4 in flight) ----
        float4 ld[9][2];
        #pragma unroll
        for (int s = 0; s < 4; ++s) {
            ld[s][0]     = *(const float4*)(xi + 16 * s);
            ld[s][1]     = *(const float4*)(xi + 16 * s + 4);
        }
        #pragma unroll
        for (int s = 0; s < 4; ++s) {
            ld[4 + s][0] = *(const float4*)(xj + 16 * s);
            ld[4 + s][1] = *(const float4*)(xj + 16 * s + 4);
        }
        ld[8][0] = *(const float4*)(eaR);
        ld[8][1] = *(const float4*)(eaR + 4);

        // ---- layer 1 (swapped): H^T = W1^T * concat^T;  M'=128, N'=32, K=144 + bias step ----
        f32x16 acc[4] = {};   // acc[t1]: HID rows 32*t1.., col j = l31 (batch row)
        #pragma unroll
        for (int s = 0; s < 9; ++s) {
            bf8_t b;
            b[0] = f2bf(ld[s][0].x); b[1] = f2bf(ld[s][0].y);
            b[2] = f2bf(ld[s][0].z); b[3] = f2bf(ld[s][0].w);
            b[4] = f2bf(ld[s][1].x); b[5] = f2bf(ld[s][1].y);
            b[6] = f2bf(ld[s][1].z); b[7] = f2bf(ld[s][1].w);
            #pragma unroll
            for (int t1 = 0; t1 < 4; ++t1) {
                const bf8_t a = *(const bf8_t*)(sW1 + (32 * t1 + l31) * LDW + 16 * s + 8 * g2);
                acc[t1] = __builtin_amdgcn_mfma_f32_32x32x16_bf16(a, b, acc[t1], 0, 0, 0);
            }
        }
        {   // bias K-step: concat col 144 == 1.0
            bf8_t b = {};
            b[0] = (short)(g2 == 0 ? 0x3F80 : 0);   // bf16 1.0 in slot (g2=0,e=0) <-> k=144
            #pragma unroll
            for (int t1 = 0; t1 < 4; ++t1) {
                const bf8_t a = *(const bf8_t*)(sW1 + (32 * t1 + l31) * LDW + 144 + 8 * g2);
                acc[t1] = __builtin_amdgcn_mfma_f32_32x32x16_bf16(a, b, acc[t1], 0, 0, 0);
            }
        }

        // ---- layer 2: out = H * W2;  M=32 (rows, lane-local), N=64, K=128 + bias step ----
        // A-fragment for step s is exactly regs acc[s>>1][8*(s&1) + 0..7] (prelu'd):
        // k-map f(g2,e) = 16s + 8*(e>>2) + 4*g2 + (e&3); sW2 pre-permuted to match.
        f32x16 acc2[2] = {};
        #pragma unroll
        for (int s = 0; s < 8; ++s) {
            const int t = s >> 1, rb = (s & 1) * 8;
            bf8_t a;
            #pragma unroll
            for (int e = 0; e < 8; ++e) {
                float v = acc[t][rb + e];
                v = fmaxf(v, 0.f) + alpha * fminf(v, 0.f);   // PReLU
                a[e] = f2bf(v);
            }
            #pragma unroll
            for (int t2 = 0; t2 < 2; ++t2) {
                const bf8_t bb = *(const bf8_t*)(sW2 + (32 * t2 + l31) * LDW + 16 * s + 8 * g2);
                acc2[t2] = __builtin_amdgcn_mfma_f32_32x32x16_bf16(a, bb, acc2[t2], 0, 0, 0);
            }
        }
        {   // bias K-step: H col 128 == 1.0
            bf8_t a = {};
            a[0] = (short)(g2 == 0 ? 0x3F80 : 0);
            #pragma unroll
            for (int t2 = 0; t2 < 2; ++t2) {
                const bf8_t bb = *(const bf8_t*)(sW2 + (32 * t2 + l31) * LDW + 128 + 8 * g2);
                acc2[t2] = __builtin_amdgcn_mfma_f32_32x32x16_bf16(a, bb, acc2[t2], 0, 0, 0);
            }
        }

        // ---- PReLU + store: lane holds out[row0 + m][32*t2 + l31], m=(r&3)+8*(r>>2)+4*g2 ----
        float* op = out + row0 * 64;
        #pragma unroll
        for (int t2 = 0; t2 < 2; ++t2) {
            #pragma unroll
            for (int r = 0; r < 16; ++r) {
                const int m = (r & 3) + 8 * (r >> 2) + 4 * g2;
                float v = acc2[t2][r];
                v = fmaxf(v, 0.f) + alpha * fminf(v, 0.f);
                op[(size_t)m * 64 + 32 * t2 + l31] = v;
            }
        }
    }
}

extern "C" void kernel_launch(void* const* d_in, const int* in_sizes, int n_in,
                              void* d_out, int out_size, void* d_ws, size_t ws_size,
                              hipStream_t stream) {
    const float* x_i  = (const float*)d_in[0];
    const float* x_j  = (const float*)d_in[1];
    const float* ea   = (const float*)d_in[2];
    const float* W1   = (const float*)d_in[3];
    const float* b1   = (const float*)d_in[4];
    const float* W2   = (const float*)d_in[5];
    const float* b2   = (const float*)d_in[6];
    const float* alph = (const float*)d_in[7];
    message_pass_kernel<<<NBLK, 256, 0, stream>>>(x_i, x_j, ea, W1, b1, W2, b2, alph,
                                                  (float*)d_out);
}